// Round 11
// baseline (1211.845 us; speedup 1.0000x reference)
//
#include <hip/hip_runtime.h>
#include <hip/hip_bf16.h>
#include <math.h>

// Problem constants (fixed by setup_inputs)
#define M_TOTAL 6272   // B*P
#define N_CS    16384  // coreset rows
#define D_DIM   384
#define BATCH   8
#define P_PATCH 784
#define KNN     9

// R19: R13 GEMM VERBATIM (best: 106us) + reduce_rescore FUSED into mindist
// via last-block-per-bx (device atomic counter, 49 lines x 128 adds — NOT
// R7's single-line contention). The last block for patch-tile bx reduces
// its 128 rows + exact fp32 rescore, OVERLAPPED with other tiles' GEMM.
// partial[] is now per-ROW keys (6272 entries); dnn/top9 scan 784/batch.
// R18 post-mortem: cooperative fusion = 1 blk/CU latency-starved (197us);
// tail buckets measured: reduce+dnn+top9 ~74us, convert+overhead ~73us.
// Ledger: scheduling 0/4, TLP>12w 0/2, global-B 0/2, tile 64x64 optimal.
// launch_bounds law: cap=512/arg2; (256,3)->170, R13 used 136.
// SPILL GATE: WRITE_SIZE must stay ~6.4MB.
#define MTILES  (M_TOTAL / 128)  // 49 patch tiles
#define NTILES2 (N_CS / 128)     // 128 cs tiles -> pvals[m][128]

typedef _Float16 half8 __attribute__((ext_vector_type(8)));
typedef float    floatx4 __attribute__((ext_vector_type(4)));

// async global->LDS, 16B per lane; LDS dest must be uniform-base + lane*16
__device__ __forceinline__ void async_copy16(const void* g, void* l) {
    __builtin_amdgcn_global_load_lds(
        (const __attribute__((address_space(1))) void*)g,
        (__attribute__((address_space(3))) void*)l, 16, 0, 0);
}

__device__ __forceinline__ unsigned long long shfl_xor_u64(unsigned long long v, int mk) {
    int lo = __shfl_xor((int)(unsigned)v, mk, 64);
    int hi = __shfl_xor((int)(unsigned)(v >> 32), mk, 64);
    return ((unsigned long long)(unsigned)hi << 32) | (unsigned)lo;
}

// ---------------- convert fp32->f16, fused cs+emb (wave per row) ----------
// Block 0 also zeroes the 49 per-bx completion counters (stream order
// guarantees they are zero before mindist starts; re-zeroed every replay).
__global__ void convert_all_kernel(const float* __restrict__ emb,
                                   const float* __restrict__ cs,
                                   _Float16* __restrict__ embh,
                                   _Float16* __restrict__ csh,
                                   float* __restrict__ cnorm,
                                   int* __restrict__ cnt) {
    if (blockIdx.x == 0 && threadIdx.x < MTILES) cnt[threadIdx.x] = 0;
    int w = threadIdx.x >> 6, lane = threadIdx.x & 63;
    int row = blockIdx.x * 4 + w;
    if (row >= N_CS + M_TOTAL) return;
    bool is_cs = row < N_CS;
    const float* r = (is_cs ? cs + (size_t)row * D_DIM
                            : emb + (size_t)(row - N_CS) * D_DIM) + lane * 6;
    float2 a = *(const float2*)r;
    float2 b = *(const float2*)(r + 2);
    float2 c = *(const float2*)(r + 4);
    union { _Float16 h[2]; unsigned u; } p0, p1, p2;
    p0.h[0] = (_Float16)a.x; p0.h[1] = (_Float16)a.y;
    p1.h[0] = (_Float16)b.x; p1.h[1] = (_Float16)b.y;
    p2.h[0] = (_Float16)c.x; p2.h[1] = (_Float16)c.y;
    unsigned* dst = (unsigned*)(is_cs ? csh + (size_t)row * D_DIM
                                      : embh + (size_t)(row - N_CS) * D_DIM) + lane * 3;
    dst[0] = p0.u; dst[1] = p1.u; dst[2] = p2.u;
    if (is_cs) {
        float s = a.x * a.x + a.y * a.y + b.x * b.x + b.y * b.y + c.x * c.x + c.y * c.y;
#pragma unroll
        for (int mk = 1; mk <= 32; mk <<= 1) s += __shfl_xor(s, mk, 64);
        if (lane == 0) cnorm[row] = s;
    }
}

// --------------------------------------------- MFMA GEMM + min/argmin ----
// R13 VERBATIM GEMM. A-operand = coreset rows (As), B = patch rows (Bs):
// C[n][m], n = cs row (min axis, IN-LANE), m = patch col. XCD partition:
// each XCD owns a FIXED set of 16 cs-tiles (1.5MB csh slice L2-resident).
// LDS rows 128B; XOR-swizzle 16B chunks p = logical ^ (row&7), staged via
// pre-swizzled GLOBAL source (linear LDS dest), read back with same XOR.
// NEW (R19): after the pvals/pidx write, last-block-per-bx does the
// 128-row reduce + exact fp32 rescore (was reduce_rescore_kernel).
__global__ __launch_bounds__(256, 3) void mindist_mfma_kernel(
    const _Float16* __restrict__ embh, const _Float16* __restrict__ csh,
    const float* __restrict__ cnorm,
    const float* __restrict__ emb, const float* __restrict__ cs,
    float* __restrict__ pvals, int* __restrict__ pidx,
    int* __restrict__ loc, unsigned long long* __restrict__ partial,
    int* __restrict__ cnt) {
    __shared__ _Float16 As[128 * 64];   // 16 KB (cs rows)
    __shared__ _Float16 Bs[128 * 64];   // 16 KB (patch rows)
    __shared__ float smv[128 * 2];
    __shared__ int   smi[128 * 2];
    __shared__ int   lastS;

    const int b    = blockIdx.x;
    const int bx   = b >> 7;                               // 0..48 patch tile
    const int by   = ((b & 7) << 4) | ((b >> 3) & 15);     // 0..127 cs tile, XCD-sliced
    const int tid  = threadIdx.x;
    const int lane = tid & 63;
    const int w    = tid >> 6;
    const int wr   = w >> 1, wc = w & 1;   // wr: cs half, wc: patch half
    const int prow0 = bx * 128;            // patch base
    const int nbase = by * 128;            // coreset base
    const int q   = lane >> 4;
    const int cl  = lane & 15;

    floatx4 acc[4][4];
#pragma unroll
    for (int mi = 0; mi < 4; ++mi)
#pragma unroll
        for (int nj = 0; nj < 4; ++nj) acc[mi][nj] = (floatx4){0.f, 0.f, 0.f, 0.f};

    // staging geometry: instruction t covers rows t*8..t*8+7 (8 lanes/row);
    // source column chunk pre-swizzled so linear LDS == swizzled layout.
    const int srow = lane >> 3;                       // 0..7 row within inst
    const int scol = ((lane & 7) ^ srow) * 8;         // f16 col offset 0..56

    // 16 A-insts (waves 0,1) + 16 B-insts (waves 2,3); 8 per wave per K-step
#define STAGE(KK)                                                             \
    {                                                                         \
        _Pragma("unroll")                                                     \
        for (int i = 0; i < 8; ++i) {                                         \
            int t = (w & 1) * 8 + i;          /* 0..15 within A or B */       \
            int r = t * 8 + srow;                                             \
            if (w < 2) {                                                      \
                async_copy16(csh + (size_t)(nbase + r) * D_DIM + (KK) + scol, \
                             &As[t * 512 + lane * 8]);                        \
            } else {                                                          \
                async_copy16(embh + (size_t)(prow0 + r) * D_DIM + (KK) + scol,\
                             &Bs[t * 512 + lane * 8]);                        \
            }                                                                 \
        }                                                                     \
    }

    // one K=64 step: 2 sub-chunks (ks=0,1), 16 MFMAs each
#define COMPUTE()                                                             \
    {                                                                         \
        _Pragma("unroll")                                                     \
        for (int ks = 0; ks < 2; ++ks) {                                      \
            half8 af[4], bf[4];                                               \
            _Pragma("unroll")                                                 \
            for (int mi = 0; mi < 4; ++mi) {                                  \
                int R = wr * 64 + mi * 16 + cl;                               \
                int p = (ks * 4 + q) ^ (R & 7);                               \
                af[mi] = *(const half8*)&As[R * 64 + p * 8];                  \
            }                                                                 \
            _Pragma("unroll")                                                 \
            for (int nj = 0; nj < 4; ++nj) {                                  \
                int C = wc * 64 + nj * 16 + cl;                               \
                int p = (ks * 4 + q) ^ (C & 7);                               \
                bf[nj] = *(const half8*)&Bs[C * 64 + p * 8];                  \
            }                                                                 \
            _Pragma("unroll")                                                 \
            for (int mi = 0; mi < 4; ++mi)                                    \
                _Pragma("unroll")                                             \
                for (int nj = 0; nj < 4; ++nj)                                \
                    acc[mi][nj] = __builtin_amdgcn_mfma_f32_16x16x32_f16(     \
                        af[mi], bf[nj], acc[mi][nj], 0, 0, 0);                \
        }                                                                     \
    }

    // 6 K-steps of 64; single buffer, 2 barriers/step (m97 structure).
#pragma unroll 1
    for (int kk = 0; kk < D_DIM; kk += 64) {
        __syncthreads();          // previous compute done, buffer free
        STAGE(kk);
        __syncthreads();          // compiler drains vmcnt(0): chunk landed
        COMPUTE();
    }
#undef STAGE
#undef COMPUTE

    // epilogue: per PATCH col, min/argmin over this wave's 64 cs rows.
    // acc[mi][nj][r] = C[n][m], n = nbase + wr*64 + mi*16 + q*4 + r (IN-LANE
    // over mi,r, ascending), m = prow0 + wc*64 + nj*16 + cl.
    float cn16[4][4];
#pragma unroll
    for (int mi = 0; mi < 4; ++mi)
#pragma unroll
        for (int r = 0; r < 4; ++r)
            cn16[mi][r] = cnorm[nbase + wr * 64 + mi * 16 + q * 4 + r];

    const int nb_lane = nbase + wr * 64 + q * 4;
#pragma unroll
    for (int nj = 0; nj < 4; ++nj) {
        float v = 3.4e38f; int idx = 0x7fffffff;
#pragma unroll
        for (int mi = 0; mi < 4; ++mi)
#pragma unroll
            for (int r = 0; r < 4; ++r) {
                float d = cn16[mi][r] - 2.f * acc[mi][nj][r];
                if (d < v) { v = d; idx = nb_lane + mi * 16 + r; }
            }
        // cross-q reduce: lane bits 4,5
#pragma unroll
        for (int mk = 16; mk <= 32; mk <<= 1) {
            float v2 = __shfl_xor(v, mk, 64);
            int   i2 = __shfl_xor(idx, mk, 64);
            if (v2 < v || (v2 == v && i2 < idx)) { v = v2; idx = i2; }
        }
        if (q == 0) {
            int pl = wc * 64 + nj * 16 + cl;   // patch col within block
            smv[pl * 2 + wr] = v;
            smi[pl * 2 + wr] = idx;
        }
    }
    __syncthreads();
    if (tid < 128) {
        float v = smv[tid * 2];      int i = smi[tid * 2];
        float v1 = smv[tid * 2 + 1]; int i1 = smi[tid * 2 + 1];
        if (v1 < v) { v = v1; i = i1; }   // wr0 cs idx always < wr1 cs idx
        pvals[(size_t)(prow0 + tid) * NTILES2 + by] = v;
        pidx[(size_t)(prow0 + tid) * NTILES2 + by]  = i;
    }

    // ---- R19: last block for this bx reduces + rescores its 128 rows ----
    __threadfence();     // publish this block's pvals/pidx (device scope)
    __syncthreads();     // all threads' writes fenced before the atomic
    if (tid == 0) lastS = (atomicAdd(&cnt[bx], 1) == 127) ? 1 : 0;
    __syncthreads();
    if (!lastS) return;
    __threadfence();     // acquire side: other blocks' writes now visible

    // 4 waves x 32 rows; per-row code identical to old reduce_rescore.
    // Iterations independent -> loads pipeline across rows (no barrier).
    for (int rr = w; rr < 128; rr += 4) {
        int m = prow0 + rr;
        float v = pvals[(size_t)m * NTILES2 + lane];
        int   i = pidx[(size_t)m * NTILES2 + lane];
        {
            float v1 = pvals[(size_t)m * NTILES2 + lane + 64];
            int   i1 = pidx[(size_t)m * NTILES2 + lane + 64];
            if (v1 < v) { v = v1; i = i1; }   // first-half idx always smaller
        }
#pragma unroll
        for (int mk = 1; mk <= 32; mk <<= 1) {
            float v2 = __shfl_xor(v, mk, 64);
            int   i2 = __shfl_xor(i, mk, 64);
            if (v2 < v || (v2 == v && i2 < i)) { v = v2; i = i2; }
        }
        // exact fp32 distance to the selected coreset row
        const float* a  = emb + (size_t)m * D_DIM;
        const float* bp = cs + (size_t)i * D_DIM;
        float s = 0.f;
#pragma unroll
        for (int t = 0; t < D_DIM / 64; ++t) {
            float d = a[lane + t * 64] - bp[lane + t * 64];
            s += d * d;
        }
#pragma unroll
        for (int mk = 1; mk <= 32; mk <<= 1) s += __shfl_xor(s, mk, 64);
        if (lane == 0) {
            loc[m] = i;
            int pp = m % P_PATCH;
            partial[m] = ((unsigned long long)__float_as_uint(sqrtf(s)) << 32) |
                         (unsigned)(0x7fffffff - pp);
        }
    }
}

// -------------------- d_nn: 8 queries x 16384 coreset (coalesced GEMV) ----
// partial is now per-ROW (784 keys per batch); same key packing, same
// max-then-smallest-patch tie-break as before.
__global__ void dnn_kernel(const float* __restrict__ cs,
                           const float* __restrict__ cnorm,
                           const unsigned long long* __restrict__ partial,
                           const int* __restrict__ loc,
                           float* __restrict__ dmat) {
    __shared__ int bnnS[BATCH];
    {   // per-block argmax recompute: 32 lanes per batch over 784 entries
        int bb = threadIdx.x >> 5, l32 = threadIdx.x & 31;
        unsigned long long best = 0ull;
        for (int j = l32; j < P_PATCH; j += 32) {
            unsigned long long k = partial[bb * P_PATCH + j];
            if (k > best) best = k;
        }
#pragma unroll
        for (int mk = 1; mk <= 16; mk <<= 1) {
            unsigned long long o = shfl_xor_u64(best, mk);
            if (o > best) best = o;
        }
        if (l32 == 0) {
            int p = 0x7fffffff - (unsigned)(best & 0xffffffffull);
            bnnS[bb] = loc[bb * P_PATCH + p];
        }
    }
    __syncthreads();

    int lane = threadIdx.x & 63;
    int gw = (blockIdx.x * 256 + threadIdx.x) >> 6;  // 0..1023
    float qv[BATCH][6];
#pragma unroll
    for (int b = 0; b < BATCH; ++b) {
        const float* qr = cs + (size_t)bnnS[b] * D_DIM + lane * 6;
#pragma unroll
        for (int j = 0; j < 6; ++j) qv[b][j] = qr[j];
    }
    for (int n = gw; n < N_CS; n += 1024) {
        const float* r = cs + (size_t)n * D_DIM + lane * 6;
        float x[6];
#pragma unroll
        for (int j = 0; j < 6; ++j) x[j] = r[j];
        float s[BATCH];
#pragma unroll
        for (int b = 0; b < BATCH; ++b) {
            float t = 0.f;
#pragma unroll
            for (int j = 0; j < 6; ++j) t += x[j] * qv[b][j];
            s[b] = t;
        }
#pragma unroll
        for (int b = 0; b < BATCH; ++b)
#pragma unroll
            for (int mk = 1; mk <= 32; mk <<= 1) s[b] += __shfl_xor(s[b], mk, 64);
        if (lane < BATCH) {
            float sv = s[0];
#pragma unroll
            for (int b = 1; b < BATCH; ++b) sv = (lane == b) ? s[b] : sv;
            dmat[(size_t)lane * N_CS + n] = cnorm[n] - 2.f * sv;  // -qnorm shift: order-safe
        }
    }
}

// ----------------------- top-9 merge + exact dsup + softmax weighting ----
__device__ inline void merge9(float* av, int* ai, const float* bv, const int* bi) {
    float mv[KNN]; int mi[KNN];
    int x = 0, y = 0;
#pragma unroll
    for (int k = 0; k < KNN; ++k) {
        bool ta = (av[x] < bv[y]) || (av[x] == bv[y] && ai[x] < bi[y]);
        if (ta) { mv[k] = av[x]; mi[k] = ai[x]; ++x; }
        else    { mv[k] = bv[y]; mi[k] = bi[y]; ++y; }
    }
#pragma unroll
    for (int k = 0; k < KNN; ++k) { av[k] = mv[k]; ai[k] = mi[k]; }
}

__global__ void top9_final_kernel(const float* __restrict__ dmat,
                                  const float* __restrict__ emb,
                                  const float* __restrict__ cs,
                                  const unsigned long long* __restrict__ partial,
                                  float* __restrict__ out) {
    int b = blockIdx.x;
    int tid = threadIdx.x;  // 512
    __shared__ float lv[512][KNN];
    __shared__ int   li[512][KNN];
    __shared__ float mf[D_DIM];
    __shared__ float dsup[KNN];
    __shared__ float bscoreS;
    __shared__ int   bpatchS;

    if (tid < 64) {  // argmax recompute for this batch (784 per-row keys)
        unsigned long long best = 0ull;
        for (int j = tid; j < P_PATCH; j += 64) {
            unsigned long long k = partial[b * P_PATCH + j];
            if (k > best) best = k;
        }
#pragma unroll
        for (int mk = 1; mk <= 32; mk <<= 1) {
            unsigned long long o = shfl_xor_u64(best, mk);
            if (o > best) best = o;
        }
        if (tid == 0) {
            bpatchS = 0x7fffffff - (unsigned)(best & 0xffffffffull);
            bscoreS = __uint_as_float((unsigned)(best >> 32));
        }
    }
    __syncthreads();
    int mp = bpatchS;
    const float* frow = emb + (size_t)(b * P_PATCH + mp) * D_DIM;
    for (int i = tid; i < D_DIM; i += 512) mf[i] = frow[i];

    float tv[KNN]; int ti[KNN];
#pragma unroll
    for (int k = 0; k < KNN; ++k) { tv[k] = 3.4e38f; ti[k] = 0x7fffffff; }
    for (int n = tid; n < N_CS; n += 512) {   // ascending n per thread
        float d = dmat[(size_t)b * N_CS + n];
        if (d < tv[KNN - 1] || (d == tv[KNN - 1] && n < ti[KNN - 1])) {
            tv[KNN - 1] = d; ti[KNN - 1] = n;
#pragma unroll
            for (int k = KNN - 1; k > 0; --k) {
                if (tv[k] < tv[k - 1] || (tv[k] == tv[k - 1] && ti[k] < ti[k - 1])) {
                    float fv = tv[k]; tv[k] = tv[k - 1]; tv[k - 1] = fv;
                    int   iv = ti[k]; ti[k] = ti[k - 1]; ti[k - 1] = iv;
                }
            }
        }
    }
#pragma unroll
    for (int k = 0; k < KNN; ++k) { lv[tid][k] = tv[k]; li[tid][k] = ti[k]; }
    __syncthreads();
    for (int off = 256; off > 0; off >>= 1) {
        if (tid < off) {
            float av[KNN]; int ai[KNN]; float bv2[KNN]; int bi2[KNN];
#pragma unroll
            for (int k = 0; k < KNN; ++k) {
                av[k]  = lv[tid][k];        ai[k]  = li[tid][k];
                bv2[k] = lv[tid + off][k];  bi2[k] = li[tid + off][k];
            }
            merge9(av, ai, bv2, bi2);
#pragma unroll
            for (int k = 0; k < KNN; ++k) { lv[tid][k] = av[k]; li[tid][k] = ai[k]; }
        }
        __syncthreads();
    }
    // exact fp32 distances to the 9 support rows: 32 lanes per neighbor
    {
        int k      = tid >> 5;   // 0..15
        int lane32 = tid & 31;
        if (k < KNN) {
            int idx = li[0][k];
            const float* r = cs + (size_t)idx * D_DIM;
            float s = 0.f;
            for (int i = lane32; i < D_DIM; i += 32) {
                float df = mf[i] - r[i];
                s += df * df;
            }
#pragma unroll
            for (int mk = 1; mk <= 16; mk <<= 1) s += __shfl_xor(s, mk, 64);
            if (lane32 == 0) dsup[k] = sqrtf(fmaxf(s, 0.f));
        }
    }
    __syncthreads();
    if (tid == 0) {
        float mx = dsup[0];
        for (int k = 1; k < KNN; ++k) mx = fmaxf(mx, dsup[k]);
        float sum = 0.f, e0 = 0.f;
        for (int k = 0; k < KNN; ++k) {
            float e = expf(dsup[k] - mx);
            sum += e;
            if (k == 0) e0 = e;
        }
        out[b] = (1.f - e0 / sum) * bscoreS;
    }
}

// ------------------------------------------------------------- launcher ----
extern "C" void kernel_launch(void* const* d_in, const int* in_sizes, int n_in,
                              void* d_out, int out_size, void* d_ws, size_t ws_size,
                              hipStream_t stream) {
    (void)in_sizes; (void)n_in; (void)out_size; (void)ws_size;
    const float* emb = (const float*)d_in[0];
    const float* cs  = (const float*)d_in[1];
    float* out = (float*)d_out;

    // workspace layout (~24.6 MB)
    char* p = (char*)d_ws;
    float* cnorm  = (float*)p;  p += (size_t)N_CS * 4;                     // 64 KB
    float* pvals  = (float*)p;  p += (size_t)M_TOTAL * NTILES2 * 4;        // 3.2 MB
    int*   pidx   = (int*)p;    p += (size_t)M_TOTAL * NTILES2 * 4;        // 3.2 MB
    int*   loc    = (int*)p;    p += (size_t)M_TOTAL * 4;
    p = (char*)(((size_t)p + 7) & ~(size_t)7);
    unsigned long long* partial = (unsigned long long*)p;
    p += (size_t)M_TOTAL * 8;                                              // 50 KB (per-row keys)
    int* cnt      = (int*)p;    p += MTILES * 4;                           // 196 B
    p = (char*)(((size_t)p + 15) & ~(size_t)15);
    float* dmat   = (float*)p;  p += (size_t)BATCH * N_CS * 4;             // 512 KB
    p = (char*)(((size_t)p + 15) & ~(size_t)15);
    _Float16* embh = (_Float16*)p; p += (size_t)M_TOTAL * D_DIM * 2;       // 4.8 MB
    _Float16* csh  = (_Float16*)p; p += (size_t)N_CS * D_DIM * 2;          // 12.6 MB

    {
        int rows = N_CS + M_TOTAL;
        convert_all_kernel<<<(rows + 3) / 4, 256, 0, stream>>>(emb, cs, embh, csh,
                                                               cnorm, cnt);
    }
    mindist_mfma_kernel<<<MTILES * NTILES2, 256, 0, stream>>>(embh, csh, cnorm,
                                                              emb, cs,
                                                              pvals, pidx,
                                                              loc, partial, cnt);
    dnn_kernel<<<256, 256, 0, stream>>>(cs, cnorm, partial, loc, dmat);
    top9_final_kernel<<<BATCH, 512, 0, stream>>>(dmat, emb, cs, partial, out);
}

// Round 12
// 251.280 us; speedup vs baseline: 4.8227x; 4.8227x over previous
//
#include <hip/hip_runtime.h>
#include <hip/hip_bf16.h>
#include <math.h>

// Problem constants (fixed by setup_inputs)
#define M_TOTAL 6272   // B*P
#define N_CS    16384  // coreset rows
#define D_DIM   384
#define BATCH   8
#define P_PATCH 784
#define KNN     9

// R20: REVERT to R13 verbatim — best measured config (252.72us total,
// mindist 106us @ MfmaUtil 33% = the m97-structure ceiling).
// Complete ledger (why nothing else is left):
//  - scheduling 0/4: R9 2-buf, R10 3-buf counted-vmcnt, R14 8-phase,
//    R16 ratio side-effect — all null/negative on this K=384 geometry.
//  - TLP: 12 waves/CU optimal; R15 (4blk) spilled, R16 (16w) LDS-ratio loss.
//  - operand placement: LDS both operands > global-B (R11: spill; R17:
//    2x L2 traffic + latency on MFMA critical path, 177us).
//  - tile: 64x64/wave optimal (FLOP/LDS-byte=32).
//  - tail fusion 0/2 with ARCHITECTURAL causes: R18 cooperative = 1 blk/CU
//    latency collapse (197us); R19 atomic+__threadfence = device-scope
//    fence forces per-XCD L2 WRITEBACK to HBM (non-coherent L2s!) —
//    WRITE_SIZE 6.3->47.8MB, 10x serialization. NEVER fence device-scope
//    in a hot kernel on MI355X.
// launch_bounds law (R6/R11/R12/R15): total(VGPR+AGPR) cap = 512/arg2.
// (256,3) -> 170; this kernel uses 72+64=136. DO NOT raise arg2.
#define MTILES  (M_TOTAL / 128)  // 49 patch tiles
#define NTILES2 (N_CS / 128)     // 128 cs tiles -> pvals[m][128]
#define NBLK    (M_TOTAL / 4)    // 1568 reduce blocks; 784=4*196 -> one batch/block
#define PBB     196              // partial entries per batch

typedef _Float16 half8 __attribute__((ext_vector_type(8)));
typedef float    floatx4 __attribute__((ext_vector_type(4)));

// async global->LDS, 16B per lane; LDS dest must be uniform-base + lane*16
__device__ __forceinline__ void async_copy16(const void* g, void* l) {
    __builtin_amdgcn_global_load_lds(
        (const __attribute__((address_space(1))) void*)g,
        (__attribute__((address_space(3))) void*)l, 16, 0, 0);
}

__device__ __forceinline__ unsigned long long shfl_xor_u64(unsigned long long v, int mk) {
    int lo = __shfl_xor((int)(unsigned)v, mk, 64);
    int hi = __shfl_xor((int)(unsigned)(v >> 32), mk, 64);
    return ((unsigned long long)(unsigned)hi << 32) | (unsigned)lo;
}

// ---------------- convert fp32->f16, fused cs+emb (wave per row) ----------
__global__ void convert_all_kernel(const float* __restrict__ emb,
                                   const float* __restrict__ cs,
                                   _Float16* __restrict__ embh,
                                   _Float16* __restrict__ csh,
                                   float* __restrict__ cnorm) {
    int w = threadIdx.x >> 6, lane = threadIdx.x & 63;
    int row = blockIdx.x * 4 + w;
    if (row >= N_CS + M_TOTAL) return;
    bool is_cs = row < N_CS;
    const float* r = (is_cs ? cs + (size_t)row * D_DIM
                            : emb + (size_t)(row - N_CS) * D_DIM) + lane * 6;
    float2 a = *(const float2*)r;
    float2 b = *(const float2*)(r + 2);
    float2 c = *(const float2*)(r + 4);
    union { _Float16 h[2]; unsigned u; } p0, p1, p2;
    p0.h[0] = (_Float16)a.x; p0.h[1] = (_Float16)a.y;
    p1.h[0] = (_Float16)b.x; p1.h[1] = (_Float16)b.y;
    p2.h[0] = (_Float16)c.x; p2.h[1] = (_Float16)c.y;
    unsigned* dst = (unsigned*)(is_cs ? csh + (size_t)row * D_DIM
                                      : embh + (size_t)(row - N_CS) * D_DIM) + lane * 3;
    dst[0] = p0.u; dst[1] = p1.u; dst[2] = p2.u;
    if (is_cs) {
        float s = a.x * a.x + a.y * a.y + b.x * b.x + b.y * b.y + c.x * c.x + c.y * c.y;
#pragma unroll
        for (int mk = 1; mk <= 32; mk <<= 1) s += __shfl_xor(s, mk, 64);
        if (lane == 0) cnorm[row] = s;
    }
}

// --------------------------------------------- MFMA GEMM + min/argmin ----
// A-operand = coreset rows (As), B-operand = patch rows (Bs):
// C[n][m], n = cs row (min axis, IN-LANE), m = patch col.
// XCD partition: each XCD owns a FIXED set of 16 cs-tiles (1.5MB csh slice
// L2-resident across all patch tiles). LDS rows 128B; XOR-swizzle 16B
// chunks p = logical ^ (row&7), staged via pre-swizzled GLOBAL source
// (linear LDS dest), read back with same XOR.
__global__ __launch_bounds__(256, 3) void mindist_mfma_kernel(
    const _Float16* __restrict__ embh, const _Float16* __restrict__ csh,
    const float* __restrict__ cnorm,
    float* __restrict__ pvals, int* __restrict__ pidx) {
    __shared__ _Float16 As[128 * 64];   // 16 KB (cs rows)
    __shared__ _Float16 Bs[128 * 64];   // 16 KB (patch rows)
    __shared__ float smv[128 * 2];
    __shared__ int   smi[128 * 2];

    const int b    = blockIdx.x;
    const int bx   = b >> 7;                               // 0..48 patch tile
    const int by   = ((b & 7) << 4) | ((b >> 3) & 15);     // 0..127 cs tile, XCD-sliced
    const int tid  = threadIdx.x;
    const int lane = tid & 63;
    const int w    = tid >> 6;
    const int wr   = w >> 1, wc = w & 1;   // wr: cs half, wc: patch half
    const int prow0 = bx * 128;            // patch base
    const int nbase = by * 128;            // coreset base
    const int q   = lane >> 4;
    const int cl  = lane & 15;

    floatx4 acc[4][4];
#pragma unroll
    for (int mi = 0; mi < 4; ++mi)
#pragma unroll
        for (int nj = 0; nj < 4; ++nj) acc[mi][nj] = (floatx4){0.f, 0.f, 0.f, 0.f};

    // staging geometry: instruction t covers rows t*8..t*8+7 (8 lanes/row);
    // source column chunk pre-swizzled so linear LDS == swizzled layout.
    const int srow = lane >> 3;                       // 0..7 row within inst
    const int scol = ((lane & 7) ^ srow) * 8;         // f16 col offset 0..56

    // 16 A-insts (waves 0,1) + 16 B-insts (waves 2,3); 8 per wave per K-step
#define STAGE(KK)                                                             \
    {                                                                         \
        _Pragma("unroll")                                                     \
        for (int i = 0; i < 8; ++i) {                                         \
            int t = (w & 1) * 8 + i;          /* 0..15 within A or B */       \
            int r = t * 8 + srow;                                             \
            if (w < 2) {                                                      \
                async_copy16(csh + (size_t)(nbase + r) * D_DIM + (KK) + scol, \
                             &As[t * 512 + lane * 8]);                        \
            } else {                                                          \
                async_copy16(embh + (size_t)(prow0 + r) * D_DIM + (KK) + scol,\
                             &Bs[t * 512 + lane * 8]);                        \
            }                                                                 \
        }                                                                     \
    }

    // one K=64 step: 2 sub-chunks (ks=0,1), 16 MFMAs each
#define COMPUTE()                                                             \
    {                                                                         \
        _Pragma("unroll")                                                     \
        for (int ks = 0; ks < 2; ++ks) {                                      \
            half8 af[4], bf[4];                                               \
            _Pragma("unroll")                                                 \
            for (int mi = 0; mi < 4; ++mi) {                                  \
                int R = wr * 64 + mi * 16 + cl;                               \
                int p = (ks * 4 + q) ^ (R & 7);                               \
                af[mi] = *(const half8*)&As[R * 64 + p * 8];                  \
            }                                                                 \
            _Pragma("unroll")                                                 \
            for (int nj = 0; nj < 4; ++nj) {                                  \
                int C = wc * 64 + nj * 16 + cl;                               \
                int p = (ks * 4 + q) ^ (C & 7);                               \
                bf[nj] = *(const half8*)&Bs[C * 64 + p * 8];                  \
            }                                                                 \
            _Pragma("unroll")                                                 \
            for (int mi = 0; mi < 4; ++mi)                                    \
                _Pragma("unroll")                                             \
                for (int nj = 0; nj < 4; ++nj)                                \
                    acc[mi][nj] = __builtin_amdgcn_mfma_f32_16x16x32_f16(     \
                        af[mi], bf[nj], acc[mi][nj], 0, 0, 0);                \
        }                                                                     \
    }

    // 6 K-steps of 64; single buffer, 2 barriers/step (m97 structure).
#pragma unroll 1
    for (int kk = 0; kk < D_DIM; kk += 64) {
        __syncthreads();          // previous compute done, buffer free
        STAGE(kk);
        __syncthreads();          // compiler drains vmcnt(0): chunk landed
        COMPUTE();
    }
#undef STAGE
#undef COMPUTE

    // epilogue: per PATCH col, min/argmin over this wave's 64 cs rows.
    // acc[mi][nj][r] = C[n][m], n = nbase + wr*64 + mi*16 + q*4 + r (IN-LANE
    // over mi,r, ascending), m = prow0 + wc*64 + nj*16 + cl.
    float cn16[4][4];
#pragma unroll
    for (int mi = 0; mi < 4; ++mi)
#pragma unroll
        for (int r = 0; r < 4; ++r)
            cn16[mi][r] = cnorm[nbase + wr * 64 + mi * 16 + q * 4 + r];

    const int nb_lane = nbase + wr * 64 + q * 4;
#pragma unroll
    for (int nj = 0; nj < 4; ++nj) {
        float v = 3.4e38f; int idx = 0x7fffffff;
#pragma unroll
        for (int mi = 0; mi < 4; ++mi)
#pragma unroll
            for (int r = 0; r < 4; ++r) {
                float d = cn16[mi][r] - 2.f * acc[mi][nj][r];
                if (d < v) { v = d; idx = nb_lane + mi * 16 + r; }
            }
        // cross-q reduce: lane bits 4,5
#pragma unroll
        for (int mk = 16; mk <= 32; mk <<= 1) {
            float v2 = __shfl_xor(v, mk, 64);
            int   i2 = __shfl_xor(idx, mk, 64);
            if (v2 < v || (v2 == v && i2 < idx)) { v = v2; idx = i2; }
        }
        if (q == 0) {
            int pl = wc * 64 + nj * 16 + cl;   // patch col within block
            smv[pl * 2 + wr] = v;
            smi[pl * 2 + wr] = idx;
        }
    }
    __syncthreads();
    if (tid < 128) {
        float v = smv[tid * 2];      int i = smi[tid * 2];
        float v1 = smv[tid * 2 + 1]; int i1 = smi[tid * 2 + 1];
        if (v1 < v) { v = v1; i = i1; }   // wr0 cs idx always < wr1 cs idx
        pvals[(size_t)(prow0 + tid) * NTILES2 + by] = v;
        pidx[(size_t)(prow0 + tid) * NTILES2 + by]  = i;
    }
}

// ---- partial-min reduce + EXACT fp32 rescore + block-level argmax -------
// partial[block] = max over the block's 4 rows of (score_bits<<32)|(~patch):
// NO atomics (R7: 1568 device atomicMax on one 64B line bounced across
// XCDs, ~65 us serialization; R19: device fences force L2 writeback).
// dnn/top9 re-scan the 12.5 KB array instead.
__global__ void reduce_rescore_kernel(const float* __restrict__ pvals,
                                      const int* __restrict__ pidx,
                                      const float* __restrict__ emb,
                                      const float* __restrict__ cs,
                                      int* __restrict__ loc,
                                      unsigned long long* __restrict__ partial) {
    __shared__ unsigned long long keys[4];
    int w = threadIdx.x >> 6, lane = threadIdx.x & 63;
    int m = blockIdx.x * 4 + w;
    // 128 partials per row: two per lane (by=lane and by=lane+64; idx of
    // the first is always smaller, so strict < keeps the tie-break exact)
    float v = pvals[(size_t)m * NTILES2 + lane];
    int   i = pidx[(size_t)m * NTILES2 + lane];
    {
        float v1 = pvals[(size_t)m * NTILES2 + lane + 64];
        int   i1 = pidx[(size_t)m * NTILES2 + lane + 64];
        if (v1 < v) { v = v1; i = i1; }
    }
#pragma unroll
    for (int mk = 1; mk <= 32; mk <<= 1) {
        float v2 = __shfl_xor(v, mk, 64);
        int   i2 = __shfl_xor(i, mk, 64);
        if (v2 < v || (v2 == v && i2 < i)) { v = v2; i = i2; }
    }
    // exact fp32 distance to the selected coreset row
    const float* a = emb + (size_t)m * D_DIM;
    const float* bp = cs + (size_t)i * D_DIM;
    float s = 0.f;
#pragma unroll
    for (int t = 0; t < D_DIM / 64; ++t) {
        float d = a[lane + t * 64] - bp[lane + t * 64];
        s += d * d;
    }
#pragma unroll
    for (int mk = 1; mk <= 32; mk <<= 1) s += __shfl_xor(s, mk, 64);
    if (lane == 0) {
        float sc = sqrtf(s);
        loc[m] = i;
        int p = m % P_PATCH;
        keys[w] = ((unsigned long long)__float_as_uint(sc) << 32) |
                  (unsigned)(0x7fffffff - p);
    }
    __syncthreads();
    if (threadIdx.x == 0) {
        unsigned long long k = keys[0];
        if (keys[1] > k) k = keys[1];
        if (keys[2] > k) k = keys[2];
        if (keys[3] > k) k = keys[3];
        partial[blockIdx.x] = k;
    }
}

// -------------------- d_nn: 8 queries x 16384 coreset (coalesced GEMV) ----
__global__ void dnn_kernel(const float* __restrict__ cs,
                           const float* __restrict__ cnorm,
                           const unsigned long long* __restrict__ partial,
                           const int* __restrict__ loc,
                           float* __restrict__ dmat) {
    __shared__ int bnnS[BATCH];
    {   // per-block argmax recompute: 32 lanes per batch over 196 entries
        int bb = threadIdx.x >> 5, l32 = threadIdx.x & 31;
        unsigned long long best = 0ull;
        for (int j = l32; j < PBB; j += 32) {
            unsigned long long k = partial[bb * PBB + j];
            if (k > best) best = k;
        }
#pragma unroll
        for (int mk = 1; mk <= 16; mk <<= 1) {
            unsigned long long o = shfl_xor_u64(best, mk);
            if (o > best) best = o;
        }
        if (l32 == 0) {
            int p = 0x7fffffff - (unsigned)(best & 0xffffffffull);
            bnnS[bb] = loc[bb * P_PATCH + p];
        }
    }
    __syncthreads();

    int lane = threadIdx.x & 63;
    int gw = (blockIdx.x * 256 + threadIdx.x) >> 6;  // 0..1023
    float qv[BATCH][6];
#pragma unroll
    for (int b = 0; b < BATCH; ++b) {
        const float* qr = cs + (size_t)bnnS[b] * D_DIM + lane * 6;
#pragma unroll
        for (int j = 0; j < 6; ++j) qv[b][j] = qr[j];
    }
    for (int n = gw; n < N_CS; n += 1024) {
        const float* r = cs + (size_t)n * D_DIM + lane * 6;
        float x[6];
#pragma unroll
        for (int j = 0; j < 6; ++j) x[j] = r[j];
        float s[BATCH];
#pragma unroll
        for (int b = 0; b < BATCH; ++b) {
            float t = 0.f;
#pragma unroll
            for (int j = 0; j < 6; ++j) t += x[j] * qv[b][j];
            s[b] = t;
        }
#pragma unroll
        for (int b = 0; b < BATCH; ++b)
#pragma unroll
            for (int mk = 1; mk <= 32; mk <<= 1) s[b] += __shfl_xor(s[b], mk, 64);
        if (lane < BATCH) {
            float sv = s[0];
#pragma unroll
            for (int b = 1; b < BATCH; ++b) sv = (lane == b) ? s[b] : sv;
            dmat[(size_t)lane * N_CS + n] = cnorm[n] - 2.f * sv;  // -qnorm shift: order-safe
        }
    }
}

// ----------------------- top-9 merge + exact dsup + softmax weighting ----
__device__ inline void merge9(float* av, int* ai, const float* bv, const int* bi) {
    float mv[KNN]; int mi[KNN];
    int x = 0, y = 0;
#pragma unroll
    for (int k = 0; k < KNN; ++k) {
        bool ta = (av[x] < bv[y]) || (av[x] == bv[y] && ai[x] < bi[y]);
        if (ta) { mv[k] = av[x]; mi[k] = ai[x]; ++x; }
        else    { mv[k] = bv[y]; mi[k] = bi[y]; ++y; }
    }
#pragma unroll
    for (int k = 0; k < KNN; ++k) { av[k] = mv[k]; ai[k] = mi[k]; }
}

__global__ void top9_final_kernel(const float* __restrict__ dmat,
                                  const float* __restrict__ emb,
                                  const float* __restrict__ cs,
                                  const unsigned long long* __restrict__ partial,
                                  float* __restrict__ out) {
    int b = blockIdx.x;
    int tid = threadIdx.x;  // 512
    __shared__ float lv[512][KNN];
    __shared__ int   li[512][KNN];
    __shared__ float mf[D_DIM];
    __shared__ float dsup[KNN];
    __shared__ float bscoreS;
    __shared__ int   bpatchS;

    if (tid < 64) {  // argmax recompute for this batch
        unsigned long long best = 0ull;
        for (int j = tid; j < PBB; j += 64) {
            unsigned long long k = partial[b * PBB + j];
            if (k > best) best = k;
        }
#pragma unroll
        for (int mk = 1; mk <= 32; mk <<= 1) {
            unsigned long long o = shfl_xor_u64(best, mk);
            if (o > best) best = o;
        }
        if (tid == 0) {
            bpatchS = 0x7fffffff - (unsigned)(best & 0xffffffffull);
            bscoreS = __uint_as_float((unsigned)(best >> 32));
        }
    }
    __syncthreads();
    int mp = bpatchS;
    const float* frow = emb + (size_t)(b * P_PATCH + mp) * D_DIM;
    for (int i = tid; i < D_DIM; i += 512) mf[i] = frow[i];

    float tv[KNN]; int ti[KNN];
#pragma unroll
    for (int k = 0; k < KNN; ++k) { tv[k] = 3.4e38f; ti[k] = 0x7fffffff; }
    for (int n = tid; n < N_CS; n += 512) {   // ascending n per thread
        float d = dmat[(size_t)b * N_CS + n];
        if (d < tv[KNN - 1] || (d == tv[KNN - 1] && n < ti[KNN - 1])) {
            tv[KNN - 1] = d; ti[KNN - 1] = n;
#pragma unroll
            for (int k = KNN - 1; k > 0; --k) {
                if (tv[k] < tv[k - 1] || (tv[k] == tv[k - 1] && ti[k] < ti[k - 1])) {
                    float fv = tv[k]; tv[k] = tv[k - 1]; tv[k - 1] = fv;
                    int   iv = ti[k]; ti[k] = ti[k - 1]; ti[k - 1] = iv;
                }
            }
        }
    }
#pragma unroll
    for (int k = 0; k < KNN; ++k) { lv[tid][k] = tv[k]; li[tid][k] = ti[k]; }
    __syncthreads();
    for (int off = 256; off > 0; off >>= 1) {
        if (tid < off) {
            float av[KNN]; int ai[KNN]; float bv2[KNN]; int bi2[KNN];
#pragma unroll
            for (int k = 0; k < KNN; ++k) {
                av[k]  = lv[tid][k];        ai[k]  = li[tid][k];
                bv2[k] = lv[tid + off][k];  bi2[k] = li[tid + off][k];
            }
            merge9(av, ai, bv2, bi2);
#pragma unroll
            for (int k = 0; k < KNN; ++k) { lv[tid][k] = av[k]; li[tid][k] = ai[k]; }
        }
        __syncthreads();
    }
    // exact fp32 distances to the 9 support rows: 32 lanes per neighbor
    {
        int k      = tid >> 5;   // 0..15
        int lane32 = tid & 31;
        if (k < KNN) {
            int idx = li[0][k];
            const float* r = cs + (size_t)idx * D_DIM;
            float s = 0.f;
            for (int i = lane32; i < D_DIM; i += 32) {
                float df = mf[i] - r[i];
                s += df * df;
            }
#pragma unroll
            for (int mk = 1; mk <= 16; mk <<= 1) s += __shfl_xor(s, mk, 64);
            if (lane32 == 0) dsup[k] = sqrtf(fmaxf(s, 0.f));
        }
    }
    __syncthreads();
    if (tid == 0) {
        float mx = dsup[0];
        for (int k = 1; k < KNN; ++k) mx = fmaxf(mx, dsup[k]);
        float sum = 0.f, e0 = 0.f;
        for (int k = 0; k < KNN; ++k) {
            float e = expf(dsup[k] - mx);
            sum += e;
            if (k == 0) e0 = e;
        }
        out[b] = (1.f - e0 / sum) * bscoreS;
    }
}

// ------------------------------------------------------------- launcher ----
extern "C" void kernel_launch(void* const* d_in, const int* in_sizes, int n_in,
                              void* d_out, int out_size, void* d_ws, size_t ws_size,
                              hipStream_t stream) {
    (void)in_sizes; (void)n_in; (void)out_size; (void)ws_size;
    const float* emb = (const float*)d_in[0];
    const float* cs  = (const float*)d_in[1];
    float* out = (float*)d_out;

    // workspace layout (~24.5 MB)
    char* p = (char*)d_ws;
    float* cnorm  = (float*)p;  p += (size_t)N_CS * 4;                     // 64 KB
    float* pvals  = (float*)p;  p += (size_t)M_TOTAL * NTILES2 * 4;        // 3.2 MB
    int*   pidx   = (int*)p;    p += (size_t)M_TOTAL * NTILES2 * 4;        // 3.2 MB
    int*   loc    = (int*)p;    p += (size_t)M_TOTAL * 4;
    p = (char*)(((size_t)p + 7) & ~(size_t)7);
    unsigned long long* partial = (unsigned long long*)p; p += NBLK * 8;   // 12.5 KB
    float* dmat   = (float*)p;  p += (size_t)BATCH * N_CS * 4;             // 512 KB
    p = (char*)(((size_t)p + 15) & ~(size_t)15);
    _Float16* embh = (_Float16*)p; p += (size_t)M_TOTAL * D_DIM * 2;       // 4.8 MB
    _Float16* csh  = (_Float16*)p; p += (size_t)N_CS * D_DIM * 2;          // 12.6 MB

    {
        int rows = N_CS + M_TOTAL;
        convert_all_kernel<<<(rows + 3) / 4, 256, 0, stream>>>(emb, cs, embh, csh, cnorm);
    }
    mindist_mfma_kernel<<<MTILES * NTILES2, 256, 0, stream>>>(embh, csh, cnorm,
                                                              pvals, pidx);
    reduce_rescore_kernel<<<NBLK, 256, 0, stream>>>(pvals, pidx, emb, cs, loc, partial);
    dnn_kernel<<<256, 256, 0, stream>>>(cs, cnorm, partial, loc, dmat);
    top9_final_kernel<<<BATCH, 512, 0, stream>>>(dmat, emb, cs, partial, out);
}